// Round 4
// baseline (83.766 us; speedup 1.0000x reference)
//
#include <hip/hip_runtime.h>

// VoxelQueryAndGrouping — MI355X (gfx950), round 4
// Counting-sort queries by (b,z,y) so waves processed together share v2p
// cache lines (L1/L2 locality), + XCD-chunked block swizzle so each XCD's L2
// holds only its z-slab of v2p. Main kernel = round-3 barrier-free wave-per-
// query (ds_permute slot scatter), indexed through qid_sorted.

constexpr int ZG = 21;
constexpr int YG = 400;
constexpr int XG = 352;
constexpr int NS = 16;   // NSAMPLE
constexpr int CF = 32;   // feature channels
constexpr float R2 = 64.0f; // RADIUS^2

typedef float v4f __attribute__((ext_vector_type(4)));

__global__ __launch_bounds__(256) void pad_xyz_kernel(
    const float* __restrict__ xyz, float4* __restrict__ xyz4, int N)
{
    const int i = blockIdx.x * 256 + threadIdx.x;
    if (i < N) {
        const float* p = xyz + (size_t)i * 3;
        xyz4[i] = make_float4(p[0], p[1], p[2], 0.0f);
    }
}

__global__ __launch_bounds__(256) void zero_kernel(int* __restrict__ p, int n)
{
    const int i = blockIdx.x * 256 + threadIdx.x;
    if (i < n) p[i] = 0;
}

__global__ __launch_bounds__(256) void hist_kernel(
    const int* __restrict__ nc, int* __restrict__ hist, int M)
{
    const int m = blockIdx.x * 256 + threadIdx.x;
    if (m >= M) return;
    const int4 qc = *reinterpret_cast<const int4*>(nc + (size_t)m * 4);
    const int key = (qc.x * ZG + qc.y) * YG + qc.z;   // (b, z, y)
    atomicAdd(&hist[key], 1);
}

// Single-workgroup exclusive prefix sum over nbin counters (in place).
__global__ __launch_bounds__(1024) void scan_kernel(int* __restrict__ hist, int nbin)
{
    __shared__ int s[1024];
    const int t = threadIdx.x;
    const int chunk = (nbin + 1023) >> 10;
    const int lo = t * chunk;
    const int hi = min(lo + chunk, nbin);
    int sum = 0;
    for (int i = lo; i < hi; ++i) sum += hist[i];
    s[t] = sum;
    __syncthreads();
    for (int off = 1; off < 1024; off <<= 1) {
        const int u = (t >= off) ? s[t - off] : 0;
        __syncthreads();
        s[t] += u;
        __syncthreads();
    }
    int run = s[t] - sum;   // exclusive prefix of this thread's chunk
    for (int i = lo; i < hi; ++i) {
        const int c = hist[i];
        hist[i] = run;
        run += c;
    }
}

__global__ __launch_bounds__(256) void scatter_kernel(
    const int* __restrict__ nc, int* __restrict__ base,
    int* __restrict__ qid, int M)
{
    const int m = blockIdx.x * 256 + threadIdx.x;
    if (m >= M) return;
    const int4 qc = *reinterpret_cast<const int4*>(nc + (size_t)m * 4);
    const int key = (qc.x * ZG + qc.y) * YG + qc.z;
    const int pos = atomicAdd(&base[key], 1);   // order within bin: arbitrary, OK
    qid[pos] = m;
}

__global__ __launch_bounds__(256) void vqg_kernel(
    const int*    __restrict__ new_coords,     // (M,4) [b,z,y,x]
    const float4* __restrict__ xyz4,           // (N,4) staged
    const int*    __restrict__ xyz_batch_cnt,  // (B,)
    const float*  __restrict__ new_xyz,        // (M,3)
    const float*  __restrict__ features,       // (N,CF)
    const int*    __restrict__ v2p,            // (B,ZG,YG,XG)
    const int*    __restrict__ qid,            // (M,) sorted query ids
    float* __restrict__ out_feat,              // (M,CF,NS)
    float* __restrict__ out_xyz,               // (M,3,NS)
    float* __restrict__ out_empty,             // (M,)
    int M)
{
    const int lane = threadIdx.x & 63;
    const int wid  = threadIdx.x >> 6;
    // XCD-chunked swizzle: give each XCD a contiguous range of the sorted
    // order so its private L2 only holds one z-slab of v2p.
    const int nwg = gridDim.x;
    int bid = blockIdx.x;
    if ((nwg & 7) == 0) bid = (bid & 7) * (nwg >> 3) + (bid >> 3);
    const int slot = bid * 4 + wid;
    if (slot >= M) return;          // wave-uniform; no barriers anywhere
    const int m = qid[slot];

    const int4 qc = *reinterpret_cast<const int4*>(new_coords + (size_t)m * 4);
    const int b = qc.x, zc = qc.y, yc = qc.z, xc = qc.w;
    const float qx = new_xyz[m * 3 + 0];
    const float qy = new_xyz[m * 3 + 1];
    const float qz = new_xyz[m * 3 + 2];
    int boff = 0;
    for (int i = 0; i < b; ++i) boff += xyz_batch_cnt[i];
    const int* __restrict__ gb = v2p + (size_t)b * (ZG * YG * XG);

    // ---- fused neighbor scan (reference order: dz slowest, dx fastest) ----
    const int n0 = lane;
    const int n1 = 64 + lane;
    int pidx0 = -1, pidx1 = -1;
    {
        const int z = zc + (n0 / 25 - 2);
        const int y = yc + ((n0 / 5) % 5 - 2);
        const int x = xc + (n0 % 5 - 2);
        if ((unsigned)z < (unsigned)ZG && (unsigned)y < (unsigned)YG &&
            (unsigned)x < (unsigned)XG)
            pidx0 = gb[((size_t)z * YG + y) * XG + x];
    }
    if (n1 < 125) {
        const int z = zc + (n1 / 25 - 2);
        const int y = yc + ((n1 / 5) % 5 - 2);
        const int x = xc + (n1 % 5 - 2);
        if ((unsigned)z < (unsigned)ZG && (unsigned)y < (unsigned)YG &&
            (unsigned)x < (unsigned)XG)
            pidx1 = gb[((size_t)z * YG + y) * XG + x];
    }

    float p0x = 0, p0y = 0, p0z = 0, p1x = 0, p1y = 0, p1z = 0;
    if (pidx0 >= 0) {
        const float4 p = xyz4[pidx0];
        p0x = p.x; p0y = p.y; p0z = p.z;
    }
    if (pidx1 >= 0) {
        const float4 p = xyz4[pidx1];
        p1x = p.x; p1y = p.y; p1z = p.z;
    }

    // Exact-match distance: ((dx*dx + dy*dy) + dz*dz), no FMA contraction.
    bool v0 = false, v1 = false;
    if (pidx0 >= 0) {
        const float dx = p0x - qx, dy = p0y - qy, dz = p0z - qz;
        v0 = __fadd_rn(__fadd_rn(__fmul_rn(dx, dx), __fmul_rn(dy, dy)),
                       __fmul_rn(dz, dz)) < R2;
    }
    if (pidx1 >= 0) {
        const float dx = p1x - qx, dy = p1y - qy, dz = p1z - qz;
        v1 = __fadd_rn(__fadd_rn(__fmul_rn(dx, dx), __fmul_rn(dy, dy)),
                       __fmul_rn(dz, dz)) < R2;
    }

    const unsigned long long below = (1ull << lane) - 1ull;
    const unsigned long long bal0 = __ballot(v0);
    const unsigned long long bal1 = __ballot(v1);
    const int c0   = (int)__popcll(bal0);
    const int cnt  = c0 + (int)__popcll(bal1);
    const int pos0 = (int)__popcll(bal0 & below);
    const int pos1 = c0 + (int)__popcll(bal1 & below);

    // Register-only ordered slot scatter via ds_permute (push).
    const int junk  = (16 + (lane & 31)) << 2;
    const int addr0 = (v0 && pos0 < NS) ? (pos0 << 2) : junk;
    const int addr1 = (v1 && pos1 < NS) ? (pos1 << 2) : junk;
    const int perm0 = __builtin_amdgcn_ds_permute(addr0, pidx0);
    const int perm1 = __builtin_amdgcn_ds_permute(addr1, pidx1);

    const int sel   = (lane < c0) ? perm0 : perm1;
    const int first = __shfl(sel, 0);
    const int cnt16 = cnt < NS ? cnt : NS;
    const int gfin  = (cnt == 0) ? boff : (((lane & 15) < cnt16) ? sel : first);

    // ---- grouped_xyz (M,3,NS): lanes 0..47, one float each ----
    if (lane < 48) {
        const int s = lane & 15;
        const int d = lane >> 4;
        const int row = __shfl(gfin, s);
        const float val = reinterpret_cast<const float*>(xyz4 + row)[d];
        __builtin_nontemporal_store(val, out_xyz + (size_t)m * 48 + d * 16 + s);
    }
    if (lane == 0)
        __builtin_nontemporal_store(cnt == 0 ? 1.0f : 0.0f, out_empty + m);

    // ---- grouped_features (M,CF,NS): direct gather, dwordx4 stores ----
    const int s0 = (lane & 3) << 2;
    const int r0 = __shfl(gfin, s0 + 0);
    const int r1 = __shfl(gfin, s0 + 1);
    const int r2 = __shfl(gfin, s0 + 2);
    const int r3 = __shfl(gfin, s0 + 3);
    float* __restrict__ of = out_feat + (size_t)m * (CF * NS);
    #pragma unroll
    for (int k = 0; k < 2; ++k) {
        const int c = k * 16 + (lane >> 2);
        v4f v;
        v[0] = features[(size_t)r0 * CF + c];
        v[1] = features[(size_t)r1 * CF + c];
        v[2] = features[(size_t)r2 * CF + c];
        v[3] = features[(size_t)r3 * CF + c];
        __builtin_nontemporal_store(
            v, reinterpret_cast<v4f*>(of + k * 256 + (lane << 2)));
    }
}

extern "C" void kernel_launch(void* const* d_in, const int* in_sizes, int n_in,
                              void* d_out, int out_size, void* d_ws, size_t ws_size,
                              hipStream_t stream) {
    const int*   new_coords    = (const int*)d_in[0];
    const float* xyz           = (const float*)d_in[1];
    const int*   xyz_batch_cnt = (const int*)d_in[2];
    const float* new_xyz       = (const float*)d_in[3];
    // d_in[4] = new_xyz_batch_cnt (unused)
    const float* features      = (const float*)d_in[5];
    const int*   v2p           = (const int*)d_in[6];

    const int M = in_sizes[0] / 4;
    const int N = in_sizes[1] / 3;
    const int B = in_sizes[2];
    const int nbin = B * ZG * YG;

    float* out_feat  = (float*)d_out;                       // M*CF*NS
    float* out_xyz   = out_feat + (size_t)M * CF * NS;      // M*3*NS
    float* out_empty = out_xyz + (size_t)M * 3 * NS;        // M

    // Workspace layout: xyz4 (N*16B) | hist (nbin*4B) | qid (M*4B)
    float4* xyz4 = (float4*)d_ws;
    int* hist = (int*)(xyz4 + N);
    int* qid  = hist + nbin;

    pad_xyz_kernel<<<(N + 255) / 256, 256, 0, stream>>>(xyz, xyz4, N);
    zero_kernel<<<(nbin + 255) / 256, 256, 0, stream>>>(hist, nbin);
    hist_kernel<<<(M + 255) / 256, 256, 0, stream>>>(new_coords, hist, M);
    scan_kernel<<<1, 1024, 0, stream>>>(hist, nbin);
    scatter_kernel<<<(M + 255) / 256, 256, 0, stream>>>(new_coords, hist, qid, M);

    const int blocks = (M + 3) / 4;   // 4 waves (queries) per block
    vqg_kernel<<<blocks, 256, 0, stream>>>(
        new_coords, xyz4, xyz_batch_cnt, new_xyz, features, v2p, qid,
        out_feat, out_xyz, out_empty, M);
}

// Round 5
// 53.427 us; speedup vs baseline: 1.5678x; 1.5678x over previous
//
#include <hip/hip_runtime.h>

// VoxelQueryAndGrouping — MI355X (gfx950), round 5
// Two queries per wave, software-interleaved to double per-wave memory-level
// parallelism (discriminates burst-drain vs CU-queue saturation models).
// Barrier-free: ds_permute ordered slot scatter + shfl broadcast (r3 scheme).
// No pre-kernels: xyz read directly (3 floats), no sort, no padding pass.

constexpr int ZG = 21;
constexpr int YG = 400;
constexpr int XG = 352;
constexpr int NS = 16;   // NSAMPLE
constexpr int CF = 32;   // feature channels
constexpr float R2 = 64.0f; // RADIUS^2

typedef float v4f __attribute__((ext_vector_type(4)));

struct QState {
    int  cnt;
    int  boff;
    int  gfin;   // per-lane slot row (lanes 0..15 meaningful)
};

__global__ __launch_bounds__(256) void vqg_kernel(
    const int*   __restrict__ new_coords,     // (M,4) [b,z,y,x]
    const float* __restrict__ xyz,            // (N,3)
    const int*   __restrict__ xyz_batch_cnt,  // (B,)
    const float* __restrict__ new_xyz,        // (M,3)
    const float* __restrict__ features,       // (N,CF)
    const int*   __restrict__ v2p,            // (B,ZG,YG,XG)
    float* __restrict__ out_feat,             // (M,CF,NS)
    float* __restrict__ out_xyz,              // (M,3,NS)
    float* __restrict__ out_empty,            // (M,)
    int M)
{
    const int lane = threadIdx.x & 63;
    const int w    = (blockIdx.x * 256 + threadIdx.x) >> 6;  // wave id
    const int m0   = w * 2;
    const int m1   = m0 + 1;
    if (m0 >= M) return;                      // wave-uniform exit
    const bool has1 = (m1 < M);

    // ---- load both queries' descriptors (wave-uniform lines) ----
    const int4 qc0 = *reinterpret_cast<const int4*>(new_coords + (size_t)m0 * 4);
    const int4 qc1 = has1 ? *reinterpret_cast<const int4*>(new_coords + (size_t)m1 * 4) : qc0;
    const float qx0 = new_xyz[m0 * 3 + 0], qy0 = new_xyz[m0 * 3 + 1], qz0 = new_xyz[m0 * 3 + 2];
    const float qx1 = has1 ? new_xyz[m1 * 3 + 0] : 0.f;
    const float qy1 = has1 ? new_xyz[m1 * 3 + 1] : 0.f;
    const float qz1 = has1 ? new_xyz[m1 * 3 + 2] : 0.f;

    int boff0 = 0, boff1 = 0;
    for (int i = 0; i < qc0.x; ++i) boff0 += xyz_batch_cnt[i];
    for (int i = 0; i < qc1.x; ++i) boff1 += xyz_batch_cnt[i];

    // ---- neighbor index decode (shared across queries) ----
    const int n0 = lane;         // pass 0 candidate
    const int n1 = 64 + lane;    // pass 1 candidate (n1 < 125 check below)
    const int dz0 = n0 / 25 - 2, dy0 = (n0 / 5) % 5 - 2, dx0 = n0 % 5 - 2;
    const int dz1 = n1 / 25 - 2, dy1 = (n1 / 5) % 5 - 2, dx1 = n1 % 5 - 2;
    const bool in1 = (n1 < 125);

    const int* __restrict__ gb0 = v2p + (size_t)qc0.x * (ZG * YG * XG);
    const int* __restrict__ gb1 = v2p + (size_t)qc1.x * (ZG * YG * XG);

    // ---- issue ALL v2p gathers (4 instructions back-to-back) ----
    int pa0 = -1, pa1 = -1, pb0 = -1, pb1 = -1;  // p{query}{pass}
    {
        const int z = qc0.y + dz0, y = qc0.z + dy0, x = qc0.w + dx0;
        if ((unsigned)z < (unsigned)ZG && (unsigned)y < (unsigned)YG && (unsigned)x < (unsigned)XG)
            pa0 = gb0[((size_t)z * YG + y) * XG + x];
    }
    {
        const int z = qc0.y + dz1, y = qc0.z + dy1, x = qc0.w + dx1;
        if (in1 && (unsigned)z < (unsigned)ZG && (unsigned)y < (unsigned)YG && (unsigned)x < (unsigned)XG)
            pa1 = gb0[((size_t)z * YG + y) * XG + x];
    }
    if (has1) {
        const int z = qc1.y + dz0, y = qc1.z + dy0, x = qc1.w + dx0;
        if ((unsigned)z < (unsigned)ZG && (unsigned)y < (unsigned)YG && (unsigned)x < (unsigned)XG)
            pb0 = gb1[((size_t)z * YG + y) * XG + x];
    }
    if (has1) {
        const int z = qc1.y + dz1, y = qc1.z + dy1, x = qc1.w + dx1;
        if (in1 && (unsigned)z < (unsigned)ZG && (unsigned)y < (unsigned)YG && (unsigned)x < (unsigned)XG)
            pb1 = gb1[((size_t)z * YG + y) * XG + x];
    }

    // ---- issue ALL candidate-point gathers (4 bursts) ----
    float a0x = 0, a0y = 0, a0z = 0, a1x = 0, a1y = 0, a1z = 0;
    float b0x = 0, b0y = 0, b0z = 0, b1x = 0, b1y = 0, b1z = 0;
    if (pa0 >= 0) { const float* p = xyz + (size_t)pa0 * 3; a0x = p[0]; a0y = p[1]; a0z = p[2]; }
    if (pa1 >= 0) { const float* p = xyz + (size_t)pa1 * 3; a1x = p[0]; a1y = p[1]; a1z = p[2]; }
    if (pb0 >= 0) { const float* p = xyz + (size_t)pb0 * 3; b0x = p[0]; b0y = p[1]; b0z = p[2]; }
    if (pb1 >= 0) { const float* p = xyz + (size_t)pb1 * 3; b1x = p[0]; b1y = p[1]; b1z = p[2]; }

    // ---- distances (exact reference association, no FMA) ----
    bool va0 = false, va1 = false, vb0 = false, vb1 = false;
    if (pa0 >= 0) {
        const float dx = a0x - qx0, dy = a0y - qy0, dz = a0z - qz0;
        va0 = __fadd_rn(__fadd_rn(__fmul_rn(dx, dx), __fmul_rn(dy, dy)), __fmul_rn(dz, dz)) < R2;
    }
    if (pa1 >= 0) {
        const float dx = a1x - qx0, dy = a1y - qy0, dz = a1z - qz0;
        va1 = __fadd_rn(__fadd_rn(__fmul_rn(dx, dx), __fmul_rn(dy, dy)), __fmul_rn(dz, dz)) < R2;
    }
    if (pb0 >= 0) {
        const float dx = b0x - qx1, dy = b0y - qy1, dz = b0z - qz1;
        vb0 = __fadd_rn(__fadd_rn(__fmul_rn(dx, dx), __fmul_rn(dy, dy)), __fmul_rn(dz, dz)) < R2;
    }
    if (pb1 >= 0) {
        const float dx = b1x - qx1, dy = b1y - qy1, dz = b1z - qz1;
        vb1 = __fadd_rn(__fadd_rn(__fmul_rn(dx, dx), __fmul_rn(dy, dy)), __fmul_rn(dz, dz)) < R2;
    }

    const unsigned long long below = (1ull << lane) - 1ull;
    const int junk = (16 + (lane & 31)) << 2;

    // ---- query 0: ordered slot scatter ----
    int cnt0, gfin0;
    {
        const unsigned long long bal0 = __ballot(va0);
        const unsigned long long bal1 = __ballot(va1);
        const int c0   = (int)__popcll(bal0);
        cnt0 = c0 + (int)__popcll(bal1);
        const int pos0 = (int)__popcll(bal0 & below);
        const int pos1 = c0 + (int)__popcll(bal1 & below);
        const int addr0 = (va0 && pos0 < NS) ? (pos0 << 2) : junk;
        const int addr1 = (va1 && pos1 < NS) ? (pos1 << 2) : junk;
        const int perm0 = __builtin_amdgcn_ds_permute(addr0, pa0);
        const int perm1 = __builtin_amdgcn_ds_permute(addr1, pa1);
        const int sel   = (lane < c0) ? perm0 : perm1;
        const int first = __shfl(sel, 0);
        const int c16   = cnt0 < NS ? cnt0 : NS;
        gfin0 = (cnt0 == 0) ? boff0 : (((lane & 15) < c16) ? sel : first);
    }
    // ---- query 1: ordered slot scatter ----
    int cnt1 = 0, gfin1 = 0;
    if (has1) {
        const unsigned long long bal0 = __ballot(vb0);
        const unsigned long long bal1 = __ballot(vb1);
        const int c0   = (int)__popcll(bal0);
        cnt1 = c0 + (int)__popcll(bal1);
        const int pos0 = (int)__popcll(bal0 & below);
        const int pos1 = c0 + (int)__popcll(bal1 & below);
        const int addr0 = (vb0 && pos0 < NS) ? (pos0 << 2) : junk;
        const int addr1 = (vb1 && pos1 < NS) ? (pos1 << 2) : junk;
        const int perm0 = __builtin_amdgcn_ds_permute(addr0, pb0);
        const int perm1 = __builtin_amdgcn_ds_permute(addr1, pb1);
        const int sel   = (lane < c0) ? perm0 : perm1;
        const int first = __shfl(sel, 0);
        const int c16   = cnt1 < NS ? cnt1 : NS;
        gfin1 = (cnt1 == 0) ? boff1 : (((lane & 15) < c16) ? sel : first);
    }

    // ---- gather rows for feature phase (both queries) ----
    const int s0lane = (lane & 3) << 2;
    const int a_r0 = __shfl(gfin0, s0lane + 0);
    const int a_r1 = __shfl(gfin0, s0lane + 1);
    const int a_r2 = __shfl(gfin0, s0lane + 2);
    const int a_r3 = __shfl(gfin0, s0lane + 3);
    const int b_r0 = __shfl(gfin1, s0lane + 0);
    const int b_r1 = __shfl(gfin1, s0lane + 1);
    const int b_r2 = __shfl(gfin1, s0lane + 2);
    const int b_r3 = __shfl(gfin1, s0lane + 3);

    // ---- grouped_xyz + empty, query 0 then 1 ----
    {
        const int s = lane & 15;
        const int d = lane >> 4;
        if (lane < 48) {
            const int row = __shfl(gfin0, s);
            __builtin_nontemporal_store(xyz[(size_t)row * 3 + d],
                                        out_xyz + (size_t)m0 * 48 + d * 16 + s);
        }
        if (lane == 0)
            __builtin_nontemporal_store(cnt0 == 0 ? 1.0f : 0.0f, out_empty + m0);
        if (has1) {
            if (lane < 48) {
                const int row = __shfl(gfin1, s);
                __builtin_nontemporal_store(xyz[(size_t)row * 3 + d],
                                            out_xyz + (size_t)m1 * 48 + d * 16 + s);
            }
            if (lane == 0)
                __builtin_nontemporal_store(cnt1 == 0 ? 1.0f : 0.0f, out_empty + m1);
        }
    }

    // ---- grouped_features: both queries, dwordx4 NT stores ----
    float* __restrict__ of0 = out_feat + (size_t)m0 * (CF * NS);
    float* __restrict__ of1 = out_feat + (size_t)m1 * (CF * NS);
    #pragma unroll
    for (int k = 0; k < 2; ++k) {
        const int c = k * 16 + (lane >> 2);
        v4f v;
        v[0] = features[(size_t)a_r0 * CF + c];
        v[1] = features[(size_t)a_r1 * CF + c];
        v[2] = features[(size_t)a_r2 * CF + c];
        v[3] = features[(size_t)a_r3 * CF + c];
        __builtin_nontemporal_store(v, reinterpret_cast<v4f*>(of0 + k * 256 + (lane << 2)));
    }
    if (has1) {
        #pragma unroll
        for (int k = 0; k < 2; ++k) {
            const int c = k * 16 + (lane >> 2);
            v4f v;
            v[0] = features[(size_t)b_r0 * CF + c];
            v[1] = features[(size_t)b_r1 * CF + c];
            v[2] = features[(size_t)b_r2 * CF + c];
            v[3] = features[(size_t)b_r3 * CF + c];
            __builtin_nontemporal_store(v, reinterpret_cast<v4f*>(of1 + k * 256 + (lane << 2)));
        }
    }
}

extern "C" void kernel_launch(void* const* d_in, const int* in_sizes, int n_in,
                              void* d_out, int out_size, void* d_ws, size_t ws_size,
                              hipStream_t stream) {
    const int*   new_coords    = (const int*)d_in[0];
    const float* xyz           = (const float*)d_in[1];
    const int*   xyz_batch_cnt = (const int*)d_in[2];
    const float* new_xyz       = (const float*)d_in[3];
    // d_in[4] = new_xyz_batch_cnt (unused)
    const float* features      = (const float*)d_in[5];
    const int*   v2p           = (const int*)d_in[6];

    const int M = in_sizes[0] / 4;

    float* out_feat  = (float*)d_out;                       // M*CF*NS
    float* out_xyz   = out_feat + (size_t)M * CF * NS;      // M*3*NS
    float* out_empty = out_xyz + (size_t)M * 3 * NS;        // M

    const int waves  = (M + 1) / 2;           // 2 queries per wave
    const int blocks = (waves + 3) / 4;       // 4 waves per block
    vqg_kernel<<<blocks, 256, 0, stream>>>(
        new_coords, xyz, xyz_batch_cnt, new_xyz, features, v2p,
        out_feat, out_xyz, out_empty, M);
}